// Round 2
// baseline (1626.068 us; speedup 1.0000x reference)
//
#include <hip/hip_runtime.h>
#include <hip/hip_bf16.h>
#include <math.h>

typedef short s16x8 __attribute__((ext_vector_type(8)));
typedef short s16x4 __attribute__((ext_vector_type(4)));
typedef float f32x4 __attribute__((ext_vector_type(4)));

#define MFMA(A,B,C) __builtin_amdgcn_mfma_f32_16x16x32_bf16((A),(B),(C),0,0,0)

typedef __attribute__((address_space(3))) unsigned int lds_u32;
typedef __attribute__((address_space(1))) const unsigned int glb_u32;
__device__ __forceinline__ void gload16(const short* g, const short* l){
  __builtin_amdgcn_global_load_lds((glb_u32*)g, (lds_u32*)l, 16, 0, 0);
}

__device__ __forceinline__ float bf2f(short u){
  unsigned int x = ((unsigned int)(unsigned short)u) << 16;
  return __builtin_bit_cast(float, x);
}
__device__ __forceinline__ short f2bf(float f){
  unsigned int x = __builtin_bit_cast(unsigned int, f);
  x += 0x7fffu + ((x >> 16) & 1u);
  return (short)(x >> 16);
}

#define FFI 1365
#define FFIP 1376

// ---------------- GEMM: C = A[M][K] * Bt[N][K]^T (+bias)(+res), m97-style gload_lds staging ----------------
template<int HAS_BIAS, int HAS_RES, int OUT_F32, int OUT_BF16>
__global__ __launch_bounds__(256) void gemm_k(
    const short* __restrict__ A, const short* __restrict__ Bt,
    const float* __restrict__ bias, const float* __restrict__ res,
    float* __restrict__ outF, short* __restrict__ outB,
    int M, int N, int K)
{
  __shared__ short As[128*32];
  __shared__ short Bs[128*32];
  const int tid = threadIdx.x;
  const int lane = tid & 63, wv = tid >> 6;
  const int g = lane >> 4, qi = lane & 15;
  const int m0 = blockIdx.x * 128, n0 = blockIdx.y * 128;
  const int wm = (wv >> 1) * 64, wn = (wv & 1) * 64;

  const int sr = tid >> 2, sc = (tid & 3) * 8;
  const short* Ag0 = A  + (size_t)(m0 + sr)*K + sc;
  const short* Ag1 = Ag0 + (size_t)64*K;
  const short* Bg0 = Bt + (size_t)(n0 + sr)*K + sc;
  const short* Bg1 = Bg0 + (size_t)64*K;
  const short* lA0 = As + wv*512;          // bytes: wv*1024
  const short* lA1 = As + 2048 + wv*512;   // rows 64..127
  const short* lB0 = Bs + wv*512;
  const short* lB1 = Bs + 2048 + wv*512;

  f32x4 acc[4][4];
  #pragma unroll
  for (int i=0;i<4;i++)
    #pragma unroll
    for (int j=0;j<4;j++) acc[i][j] = (f32x4){0.f,0.f,0.f,0.f};

  for (int k0 = 0; k0 < K; k0 += 32) {
    __syncthreads();
    gload16(Ag0 + k0, lA0);
    gload16(Ag1 + k0, lA1);
    gload16(Bg0 + k0, lB0);
    gload16(Bg1 + k0, lB1);
    __syncthreads();
    s16x8 af[4], bf[4];
    #pragma unroll
    for (int mi=0;mi<4;mi++) af[mi] = *(const s16x8*)&As[(wm+mi*16+qi)*32 + g*8];
    #pragma unroll
    for (int ni=0;ni<4;ni++) bf[ni] = *(const s16x8*)&Bs[(wn+ni*16+qi)*32 + g*8];
    #pragma unroll
    for (int mi=0;mi<4;mi++)
      #pragma unroll
      for (int ni=0;ni<4;ni++)
        acc[mi][ni] = MFMA(af[mi], bf[ni], acc[mi][ni]);
  }
  #pragma unroll
  for (int mi=0;mi<4;mi++){
    #pragma unroll
    for (int r=0;r<4;r++){
      int row = m0 + wm + mi*16 + g*4 + r;
      #pragma unroll
      for (int ni=0;ni<4;ni++){
        int col = n0 + wn + ni*16 + qi;
        float v = acc[mi][ni][r];
        if (HAS_BIAS) v += bias[col];
        if (HAS_RES)  v += res[(size_t)row*N + col];
        if (OUT_F32)  outF[(size_t)row*N + col] = v;
        if (OUT_BF16) outB[(size_t)row*N + col] = f2bf(v);
      }
    }
  }
}

// ---------------- FF1 + GEGLU fused: hg = (x@W1+b1)[:FFI] * gelu((x@W1+b1)[FFI:]) ----------------
__global__ __launch_bounds__(256) void geglu_k(
    const short* __restrict__ A, const short* __restrict__ Bt,
    const float* __restrict__ b1, short* __restrict__ hg)
{
  __shared__ short As[128*32];
  __shared__ short Ba[128*32];
  __shared__ short Bg[128*32];
  const int tid = threadIdx.x;
  const int lane = tid & 63, wv = tid >> 6;
  const int g = lane >> 4, qi = lane & 15;
  const int m0 = blockIdx.x * 128, n0 = blockIdx.y * 128;
  const int wm = (wv >> 1) * 64, wn = (wv & 1) * 64;

  const int sr = tid >> 2, sc = (tid & 3) * 8;
  const short* Ag0 = A + (size_t)(m0 + sr)*512 + sc;
  const short* Ag1 = Ag0 + (size_t)64*512;
  const short* Pa0 = Bt + (size_t)min(n0 + sr, FFI-1)*512 + sc;
  const short* Pa1 = Bt + (size_t)min(n0 + sr + 64, FFI-1)*512 + sc;
  const short* Pg0 = Bt + (size_t)min(FFI + n0 + sr, 2729)*512 + sc;
  const short* Pg1 = Bt + (size_t)min(FFI + n0 + sr + 64, 2729)*512 + sc;
  const short* lA0 = As + wv*512;
  const short* lA1 = As + 2048 + wv*512;
  const short* la0 = Ba + wv*512;
  const short* la1 = Ba + 2048 + wv*512;
  const short* lg0 = Bg + wv*512;
  const short* lg1 = Bg + 2048 + wv*512;

  f32x4 aa[4][4], ag[4][4];
  #pragma unroll
  for (int i=0;i<4;i++)
    #pragma unroll
    for (int j=0;j<4;j++){ aa[i][j]=(f32x4){0.f,0.f,0.f,0.f}; ag[i][j]=(f32x4){0.f,0.f,0.f,0.f}; }

  for (int k0 = 0; k0 < 512; k0 += 32) {
    __syncthreads();
    gload16(Ag0 + k0, lA0);
    gload16(Ag1 + k0, lA1);
    gload16(Pa0 + k0, la0);
    gload16(Pa1 + k0, la1);
    gload16(Pg0 + k0, lg0);
    gload16(Pg1 + k0, lg1);
    __syncthreads();
    s16x8 af[4], bfa[4], bfg[4];
    #pragma unroll
    for (int mi=0;mi<4;mi++) af[mi] = *(const s16x8*)&As[(wm+mi*16+qi)*32 + g*8];
    #pragma unroll
    for (int ni=0;ni<4;ni++){ bfa[ni] = *(const s16x8*)&Ba[(wn+ni*16+qi)*32 + g*8];
                              bfg[ni] = *(const s16x8*)&Bg[(wn+ni*16+qi)*32 + g*8]; }
    #pragma unroll
    for (int mi=0;mi<4;mi++)
      #pragma unroll
      for (int ni=0;ni<4;ni++){
        aa[mi][ni] = MFMA(af[mi], bfa[ni], aa[mi][ni]);
        ag[mi][ni] = MFMA(af[mi], bfg[ni], ag[mi][ni]);
      }
  }
  #pragma unroll
  for (int mi=0;mi<4;mi++){
    #pragma unroll
    for (int r=0;r<4;r++){
      int row = m0 + wm + mi*16 + g*4 + r;
      #pragma unroll
      for (int ni=0;ni<4;ni++){
        int col = n0 + wn + ni*16 + qi;
        if (col < FFI){
          float va = aa[mi][ni][r] + b1[col];
          float vg = ag[mi][ni][r] + b1[FFI+col];
          float ge = 0.5f * vg * (1.0f + erff(vg * 0.70710678118654752f));
          hg[(size_t)row*FFIP + col] = f2bf(va * ge);
        } else if (col < FFIP){
          hg[(size_t)row*FFIP + col] = 0;
        }
      }
    }
  }
}

// ---------------- rotary/xpos tables (f64 precompute) ----------------
__global__ void rope_k(float* __restrict__ tab){
  int n = blockIdx.x, dd = threadIdx.x;
  int i = dd & 31;
  double invf = pow(10000.0, -(double)i/32.0);
  double fr = (double)n * invf;
  double c = cos(fr), s = sin(fr);
  double sv = (2.0*i + 25.6)/89.6;
  double pw = ((double)n - 4096.0)/128.0;
  double xs = pow(sv, pw);
  size_t o = (size_t)n*64 + dd;
  tab[o]            = (float)(c*xs);
  tab[524288+o]     = (float)(s*xs);
  tab[2*524288+o]   = (float)(c/xs);
  tab[3*524288+o]   = (float)(s/xs);
}

// ---------------- weight transpose+cast: dst[N][Kp] bf16 from src[K][N] f32, zero-pad K..Kp ----------------
__global__ __launch_bounds__(256) void wtrans_k(
    const float* __restrict__ src, short* __restrict__ dst,
    int K, int N, int Kp, long srcStride, long dstStride)
{
  __shared__ float t[64][65];
  const float* s = src + (size_t)blockIdx.z * srcStride;
  short* d = dst + (size_t)blockIdx.z * dstStride;
  int n0 = blockIdx.x*64, k0 = blockIdx.y*64;
  int tid = threadIdx.x;
  #pragma unroll
  for (int p=0;p<4;p++){
    int task = p*256+tid;
    int r = task>>4, c = (task&15)*4;
    int k = k0 + r;
    #pragma unroll
    for (int e=0;e<4;e++){
      int n = n0+c+e;
      t[r][c+e] = (k<K && n<N) ? s[(size_t)k*N+n] : 0.f;
    }
  }
  __syncthreads();
  #pragma unroll
  for (int p=0;p<2;p++){
    int task = p*256+tid;
    int nr = task>>3, kg=(task&7)*8;
    int n = n0+nr;
    if (n < N && (k0+kg) < Kp){
      s16x8 v;
      #pragma unroll
      for (int j=0;j<8;j++) v[j] = f2bf(t[kg+j][nr]);
      *(s16x8*)(d + (size_t)n*Kp + k0 + kg) = v;
    }
  }
}

// ---------------- f32 -> bf16 cast ----------------
__global__ void cast_k(const float* __restrict__ in, short* __restrict__ out){
  int i = (blockIdx.x*256+threadIdx.x)*4;
  float4 v = *(const float4*)(in+i);
  s16x4 o = { f2bf(v.x), f2bf(v.y), f2bf(v.z), f2bf(v.w) };
  *(s16x4*)(out+i) = o;
}

// ---------------- q/k: l2norm + scale + xpos rotary ----------------
__global__ __launch_bounds__(256) void qkprep_k(
    const short* __restrict__ qkv, const float* __restrict__ tab,
    const float* __restrict__ qs, const float* __restrict__ ks,
    short* __restrict__ qrot, short* __restrict__ krot)
{
  int wv = threadIdx.x >> 6, lane = threadIdx.x & 63;
  int wid = blockIdx.x*4 + wv;
  int n = wid >> 3, h = wid & 7;
  float qv = bf2f(qkv[(size_t)n*1536 + h*64 + lane]);
  float kv = bf2f(qkv[(size_t)n*1536 + 512 + h*64 + lane]);
  float sq = qv*qv, sk = kv*kv;
  #pragma unroll
  for (int m=1;m<64;m<<=1){ sq += __shfl_xor(sq,m,64); sk += __shfl_xor(sk,m,64); }
  qv *= qs[lane] / fmaxf(sqrtf(sq), 1e-12f);
  kv *= ks[lane] / fmaxf(sqrtf(sk), 1e-12f);
  float qo = __shfl_xor(qv,32,64), ko = __shfl_xor(kv,32,64);
  float sgn = (lane<32)? -1.f : 1.f;
  size_t to = (size_t)n*64 + lane;
  float cq = tab[to], sxq = tab[524288+to], ck = tab[2*524288+to], sxk = tab[3*524288+to];
  qrot[((size_t)h*8192+n)*64+lane] = f2bf(qv*cq + sgn*qo*sxq);
  krot[((size_t)h*8192+n)*64+lane] = f2bf(kv*ck + sgn*ko*sxk);
}

// ---------------- V transpose: vt[h][d][n] ----------------
__global__ __launch_bounds__(256) void vtrans_k(const short* __restrict__ qkv, short* __restrict__ vt){
  __shared__ short t[64][72];
  int n0 = blockIdx.x*64, h = blockIdx.y;
  int tid = threadIdx.x;
  #pragma unroll
  for (int p=0;p<2;p++){
    int task = p*256+tid;
    int r = task>>3, cg = (task&7)*8;
    *(s16x8*)&t[r][cg] = *(const s16x8*)(qkv + (size_t)(n0+r)*1536 + 1024 + h*64 + cg);
  }
  __syncthreads();
  #pragma unroll
  for (int p=0;p<2;p++){
    int task = p*256+tid;
    int d = task>>3, nb = (task&7)*8;
    s16x8 v;
    #pragma unroll
    for (int j=0;j<8;j++) v[j] = t[nb+j][d];
    *(s16x8*)(vt + ((size_t)h*64+d)*8192 + n0 + nb) = v;
  }
}

// ---------------- local windowed attention (S^T = K*Q^T formulation, flash over 64-key chunks) ----------------
__global__ __launch_bounds__(256,1) void attn_k(
    const short* __restrict__ qrot, const short* __restrict__ krot,
    const short* __restrict__ vt, short* __restrict__ attn_o)
{
  __shared__ short Ks[128][72];
  __shared__ short Vs[64][136];
  const int w = blockIdx.x, h = blockIdx.y;
  const int tid = threadIdx.x, lane = tid & 63, wv = tid >> 6;
  const int g = lane >> 4, qi = lane & 15;
  const int wq0 = wv * 64;
  s16x8 qf[4][2];
  #pragma unroll
  for (int ni=0;ni<4;ni++){
    int qg = w*256 + wq0 + ni*16 + qi;
    const short* p = qrot + ((size_t)h*8192 + qg)*64 + g*8;
    qf[ni][0] = *(const s16x8*)p;
    qf[ni][1] = *(const s16x8*)(p + 32);
  }
  f32x4 oacc[4][4];
  float mrun[4], lrun[4];
  #pragma unroll
  for (int i=0;i<4;i++){
    mrun[i] = -1e30f; lrun[i] = 0.f;
    #pragma unroll
    for (int j=0;j<4;j++) oacc[i][j]=(f32x4){0.f,0.f,0.f,0.f};
  }
  const int kvbase = w*256 - 256;
  for (int s=0;s<4;s++){
    __syncthreads();
    #pragma unroll
    for (int p=0;p<4;p++){
      int task = p*256 + tid;
      {
        int r = task>>3, cg = (task&7)*8;
        int jg = kvbase + s*128 + r;
        s16x8 v = {0,0,0,0,0,0,0,0};
        if (jg>=0) v = *(const s16x8*)(krot + ((size_t)h*8192+jg)*64 + cg);
        *(s16x8*)&Ks[r][cg] = v;
      }
      {
        int dd = task>>4, cg = (task&15)*8;
        int jg = kvbase + s*128 + cg;
        s16x8 v = {0,0,0,0,0,0,0,0};
        if (jg>=0) v = *(const s16x8*)(vt + ((size_t)h*64+dd)*8192 + jg);
        *(s16x8*)&Vs[dd][cg] = v;
      }
    }
    __syncthreads();
    for (int cc=0;cc<2;cc++){
      const int jlo = (s*2+cc)*64;
      if (jlo + 63 < wq0) continue;
      if (jlo > wq0 + 319) continue;
      if (w==0 && jlo < 256) continue;
      f32x4 sacc[4][4];
      #pragma unroll
      for (int i=0;i<4;i++)
        #pragma unroll
        for (int j=0;j<4;j++) sacc[i][j]=(f32x4){0.f,0.f,0.f,0.f};
      #pragma unroll
      for (int ks=0;ks<2;ks++){
        s16x8 kf[4];
        #pragma unroll
        for (int mi=0;mi<4;mi++) kf[mi] = *(const s16x8*)&Ks[cc*64+mi*16+qi][ks*32+g*8];
        #pragma unroll
        for (int mi=0;mi<4;mi++)
          #pragma unroll
          for (int ni=0;ni<4;ni++)
            sacc[mi][ni] = MFMA(kf[mi], qf[ni][ks], sacc[mi][ni]);
      }
      const bool interior = (jlo >= wq0+63) && (jlo+63 <= wq0+256);
      float cmax[4];
      #pragma unroll
      for (int ni=0;ni<4;ni++) cmax[ni] = -1e30f;
      #pragma unroll
      for (int mi=0;mi<4;mi++)
        #pragma unroll
        for (int ni=0;ni<4;ni++)
          #pragma unroll
          for (int r=0;r<4;r++){
            float x = sacc[mi][ni][r] * 8.f;
            if (!interior){
              int j = jlo + mi*16 + g*4 + r;
              int ql = wq0 + ni*16 + qi;
              if (j < ql || j > ql+256) x = -1e30f;
            }
            sacc[mi][ni][r] = x;
            cmax[ni] = fmaxf(cmax[ni], x);
          }
      #pragma unroll
      for (int ni=0;ni<4;ni++){
        cmax[ni] = fmaxf(cmax[ni], __shfl_xor(cmax[ni],16,64));
        cmax[ni] = fmaxf(cmax[ni], __shfl_xor(cmax[ni],32,64));
      }
      float scl[4], psum[4];
      s16x8 pf[2][4];
      #pragma unroll
      for (int ni=0;ni<4;ni++){
        float mn = fmaxf(mrun[ni], cmax[ni]);
        scl[ni] = __expf(mrun[ni]-mn);
        mrun[ni] = mn;
        float ps = 0.f;
        #pragma unroll
        for (int t=0;t<2;t++)
          #pragma unroll
          for (int hh=0; hh<2; hh++){
            int mi = 2*t+hh;
            #pragma unroll
            for (int r=0;r<4;r++){
              float pv = __expf(sacc[mi][ni][r]-mn);
              ps += pv;
              pf[t][ni][hh*4+r] = f2bf(pv);
            }
          }
        psum[ni]=ps;
      }
      #pragma unroll
      for (int ni=0;ni<4;ni++){
        psum[ni] += __shfl_xor(psum[ni],16,64);
        psum[ni] += __shfl_xor(psum[ni],32,64);
        lrun[ni] = lrun[ni]*scl[ni] + psum[ni];
        #pragma unroll
        for (int mi=0;mi<4;mi++) oacc[mi][ni] *= scl[ni];
      }
      #pragma unroll
      for (int t=0;t<2;t++)
        #pragma unroll
        for (int mi=0;mi<4;mi++){
          const short* vp = &Vs[mi*16+qi][cc*64 + t*32 + g*4];
          s16x4 lo = *(const s16x4*)vp;
          s16x4 hi = *(const s16x4*)(vp+16);
          s16x8 vf = {lo[0],lo[1],lo[2],lo[3],hi[0],hi[1],hi[2],hi[3]};
          #pragma unroll
          for (int ni=0;ni<4;ni++)
            oacc[mi][ni] = MFMA(vf, pf[t][ni], oacc[mi][ni]);
        }
    }
  }
  #pragma unroll
  for (int ni=0;ni<4;ni++){
    float inv = 1.f / lrun[ni];
    int qg = w*256 + wq0 + ni*16 + qi;
    #pragma unroll
    for (int mi=0;mi<4;mi++){
      s16x4 st;
      #pragma unroll
      for (int r=0;r<4;r++) st[r] = f2bf(oacc[mi][ni][r]*inv);
      *(s16x4*)(attn_o + (size_t)qg*512 + h*64 + mi*16 + g*4) = st;
    }
  }
}

extern "C" void kernel_launch(void* const* d_in, const int* in_sizes, int n_in,
                              void* d_out, int out_size, void* d_ws, size_t ws_size,
                              hipStream_t stream)
{
  const float* x_in = (const float*)d_in[0];
  const float* Wqkv = (const float*)d_in[1];
  const float* Wo   = (const float*)d_in[2];
  const float* qsc  = (const float*)d_in[3];
  const float* ksc  = (const float*)d_in[4];
  const float* W1   = (const float*)d_in[5];
  const float* b1   = (const float*)d_in[6];
  const float* W2   = (const float*)d_in[7];
  const float* b2   = (const float*)d_in[8];
  float* xf = (float*)d_out;

  char* ws = (char*)d_ws;
  size_t off = 0;
  float* tab  = (float*)(ws + off); off += (size_t)4*8192*64*4;
  short* WqkvT= (short*)(ws + off); off += (size_t)6*1536*512*2;
  short* WoT  = (short*)(ws + off); off += (size_t)6*512*512*2;
  short* W1T  = (short*)(ws + off); off += (size_t)6*2730*512*2;
  short* W2T  = (short*)(ws + off); off += (size_t)6*512*1376*2;
  short* xbf  = (short*)(ws + off); off += (size_t)8192*512*2;
  short* qkv  = (short*)(ws + off); off += (size_t)8192*1536*2;
  short* qrot = (short*)(ws + off); off += (size_t)8*8192*64*2;
  short* krot = (short*)(ws + off); off += (size_t)8*8192*64*2;
  short* vt   = (short*)(ws + off); off += (size_t)8*8192*64*2;
  short* attno= (short*)(ws + off); off += (size_t)8192*512*2;
  short* hg   = (short*)(ws + off); off += (size_t)8192*1376*2;

  hipMemcpyAsync(xf, x_in, (size_t)8192*512*4, hipMemcpyDeviceToDevice, stream);
  rope_k<<<8192, 64, 0, stream>>>(tab);
  wtrans_k<<<dim3(24,8,6),256,0,stream>>>(Wqkv, WqkvT, 512,1536,512, (long)512*1536, (long)1536*512);
  wtrans_k<<<dim3(8,8,6),256,0,stream>>>(Wo, WoT, 512,512,512, (long)512*512,(long)512*512);
  wtrans_k<<<dim3(43,8,6),256,0,stream>>>(W1, W1T, 512,2730,512, (long)512*2730,(long)2730*512);
  wtrans_k<<<dim3(8,22,6),256,0,stream>>>(W2, W2T, 1365,512,1376, (long)1365*512,(long)512*1376);
  cast_k<<<4096,256,0,stream>>>(x_in, xbf);

  for (int l=0;l<6;l++){
    gemm_k<0,0,0,1><<<dim3(64,12),256,0,stream>>>(xbf, WqkvT + (size_t)l*1536*512,
        nullptr, nullptr, nullptr, qkv, 8192,1536,512);
    qkprep_k<<<16384,256,0,stream>>>(qkv, tab, qsc + l*64, ksc + l*64, qrot, krot);
    vtrans_k<<<dim3(128,8),256,0,stream>>>(qkv, vt);
    attn_k<<<dim3(32,8),256,0,stream>>>(qrot, krot, vt, attno);
    gemm_k<0,1,1,1><<<dim3(64,4),256,0,stream>>>(attno, WoT + (size_t)l*512*512,
        nullptr, xf, xf, xbf, 8192,512,512);
    geglu_k<<<dim3(64,11),256,0,stream>>>(xbf, W1T + (size_t)l*2730*512, b1 + (size_t)l*2730, hg);
    gemm_k<1,1,1,1><<<dim3(64,4),256,0,stream>>>(hg, W2T + (size_t)l*512*1376,
        b2 + (size_t)l*512, xf, xf, xbf, 8192,512,1376);
  }
}

// Round 3
// 1440.480 us; speedup vs baseline: 1.1288x; 1.1288x over previous
//
#include <hip/hip_runtime.h>
#include <hip/hip_bf16.h>
#include <math.h>

typedef short s16x8 __attribute__((ext_vector_type(8)));
typedef short s16x4 __attribute__((ext_vector_type(4)));
typedef float f32x4 __attribute__((ext_vector_type(4)));

#define MFMA(A,B,C) __builtin_amdgcn_mfma_f32_16x16x32_bf16((A),(B),(C),0,0,0)

typedef __attribute__((address_space(3))) unsigned int lds_u32;
typedef __attribute__((address_space(1))) const unsigned int glb_u32;
__device__ __forceinline__ void gload16(const short* g, const short* l){
  __builtin_amdgcn_global_load_lds((glb_u32*)g, (lds_u32*)l, 16, 0, 0);
}

__device__ __forceinline__ float bf2f(short u){
  unsigned int x = ((unsigned int)(unsigned short)u) << 16;
  return __builtin_bit_cast(float, x);
}
__device__ __forceinline__ short f2bf(float f){
  unsigned int x = __builtin_bit_cast(unsigned int, f);
  x += 0x7fffu + ((x >> 16) & 1u);
  return (short)(x >> 16);
}
// tanh-form gelu, overflow-safe: tanh(y) = 1 - 2/(e^{2y}+1)
__device__ __forceinline__ float gelu_t(float x){
  float u = x + 0.044715f*x*x*x;
  float e = __expf(1.5957691216057308f*u);
  float th = 1.f - 2.f/(e + 1.f);
  return 0.5f*x*(1.f + th);
}

#define FFI 1365
#define FFIP 1376

// ---------------- GEMM: C = A[M][K] * Bt[N][K]^T (+bias)(+res), 2-phase dbuf + gload_lds ----------------
template<int HAS_BIAS, int HAS_RES, int OUT_F32, int OUT_BF16>
__global__ __launch_bounds__(256) void gemm_k(
    const short* __restrict__ A, const short* __restrict__ Bt,
    const float* __restrict__ bias, const float* __restrict__ res,
    float* __restrict__ outF, short* __restrict__ outB,
    int M, int N, int K)
{
  __shared__ short As[2][128*32];
  __shared__ short Bs[2][128*32];
  const int tid = threadIdx.x;
  const int lane = tid & 63, wv = tid >> 6;
  const int g = lane >> 4, qi = lane & 15;
  const int m0 = blockIdx.x * 128, n0 = blockIdx.y * 128;
  const int wm = (wv >> 1) * 64, wn = (wv & 1) * 64;

  const int sr = tid >> 2, sc = (tid & 3) * 8;
  const short* Ag0 = A  + (size_t)(m0 + sr)*K + sc;
  const short* Ag1 = Ag0 + (size_t)64*K;
  const short* Bg0 = Bt + (size_t)(n0 + sr)*K + sc;
  const short* Bg1 = Bg0 + (size_t)64*K;

  f32x4 acc[4][4];
  #pragma unroll
  for (int i=0;i<4;i++)
    #pragma unroll
    for (int j=0;j<4;j++) acc[i][j] = (f32x4){0.f,0.f,0.f,0.f};

  auto stage = [&](int buf, int k0){
    gload16(Ag0 + k0, &As[buf][wv*512]);
    gload16(Ag1 + k0, &As[buf][2048 + wv*512]);
    gload16(Bg0 + k0, &Bs[buf][wv*512]);
    gload16(Bg1 + k0, &Bs[buf][2048 + wv*512]);
  };

  const int nt = K >> 5;
  stage(0, 0);
  __syncthreads();
  for (int t = 0; t < nt; ++t) {
    const int cur = t & 1;
    if (t + 1 < nt) stage(cur ^ 1, (t+1) << 5);
    s16x8 af[4], bf[4];
    #pragma unroll
    for (int mi=0;mi<4;mi++) af[mi] = *(const s16x8*)&As[cur][(wm+mi*16+qi)*32 + g*8];
    #pragma unroll
    for (int ni=0;ni<4;ni++) bf[ni] = *(const s16x8*)&Bs[cur][(wn+ni*16+qi)*32 + g*8];
    #pragma unroll
    for (int mi=0;mi<4;mi++)
      #pragma unroll
      for (int ni=0;ni<4;ni++)
        acc[mi][ni] = MFMA(af[mi], bf[ni], acc[mi][ni]);
    __syncthreads();
  }
  #pragma unroll
  for (int mi=0;mi<4;mi++){
    #pragma unroll
    for (int r=0;r<4;r++){
      int row = m0 + wm + mi*16 + g*4 + r;
      #pragma unroll
      for (int ni=0;ni<4;ni++){
        int col = n0 + wn + ni*16 + qi;
        float v = acc[mi][ni][r];
        if (HAS_BIAS) v += bias[col];
        if (HAS_RES)  v += res[(size_t)row*N + col];
        if (OUT_F32)  outF[(size_t)row*N + col] = v;
        if (OUT_BF16) outB[(size_t)row*N + col] = f2bf(v);
      }
    }
  }
}

// ---------------- FF1 + GEGLU fused: hg = (x@W1+b1)[:FFI] * gelu((x@W1+b1)[FFI:]) ----------------
__global__ __launch_bounds__(256) void geglu_k(
    const short* __restrict__ A, const short* __restrict__ Bt,
    const float* __restrict__ b1, short* __restrict__ hg)
{
  __shared__ short As[2][128*32];
  __shared__ short Ba[2][128*32];
  __shared__ short Bg[2][128*32];
  const int tid = threadIdx.x;
  const int lane = tid & 63, wv = tid >> 6;
  const int g = lane >> 4, qi = lane & 15;
  const int m0 = blockIdx.x * 128, n0 = blockIdx.y * 128;
  const int wm = (wv >> 1) * 64, wn = (wv & 1) * 64;

  const int sr = tid >> 2, sc = (tid & 3) * 8;
  const short* Ag0 = A + (size_t)(m0 + sr)*512 + sc;
  const short* Ag1 = Ag0 + (size_t)64*512;
  const short* Pa0 = Bt + (size_t)min(n0 + sr, FFI-1)*512 + sc;
  const short* Pa1 = Bt + (size_t)min(n0 + sr + 64, FFI-1)*512 + sc;
  const short* Pg0 = Bt + (size_t)min(FFI + n0 + sr, 2729)*512 + sc;
  const short* Pg1 = Bt + (size_t)min(FFI + n0 + sr + 64, 2729)*512 + sc;

  f32x4 aa[4][4], ag[4][4];
  #pragma unroll
  for (int i=0;i<4;i++)
    #pragma unroll
    for (int j=0;j<4;j++){ aa[i][j]=(f32x4){0.f,0.f,0.f,0.f}; ag[i][j]=(f32x4){0.f,0.f,0.f,0.f}; }

  auto stage = [&](int buf, int k0){
    gload16(Ag0 + k0, &As[buf][wv*512]);
    gload16(Ag1 + k0, &As[buf][2048 + wv*512]);
    gload16(Pa0 + k0, &Ba[buf][wv*512]);
    gload16(Pa1 + k0, &Ba[buf][2048 + wv*512]);
    gload16(Pg0 + k0, &Bg[buf][wv*512]);
    gload16(Pg1 + k0, &Bg[buf][2048 + wv*512]);
  };

  stage(0, 0);
  __syncthreads();
  for (int t = 0; t < 16; ++t) {
    const int cur = t & 1;
    if (t + 1 < 16) stage(cur ^ 1, (t+1) << 5);
    s16x8 af[4], bfa[4], bfg[4];
    #pragma unroll
    for (int mi=0;mi<4;mi++) af[mi] = *(const s16x8*)&As[cur][(wm+mi*16+qi)*32 + g*8];
    #pragma unroll
    for (int ni=0;ni<4;ni++){ bfa[ni] = *(const s16x8*)&Ba[cur][(wn+ni*16+qi)*32 + g*8];
                              bfg[ni] = *(const s16x8*)&Bg[cur][(wn+ni*16+qi)*32 + g*8]; }
    #pragma unroll
    for (int mi=0;mi<4;mi++)
      #pragma unroll
      for (int ni=0;ni<4;ni++){
        aa[mi][ni] = MFMA(af[mi], bfa[ni], aa[mi][ni]);
        ag[mi][ni] = MFMA(af[mi], bfg[ni], ag[mi][ni]);
      }
    __syncthreads();
  }
  #pragma unroll
  for (int mi=0;mi<4;mi++){
    #pragma unroll
    for (int r=0;r<4;r++){
      int row = m0 + wm + mi*16 + g*4 + r;
      #pragma unroll
      for (int ni=0;ni<4;ni++){
        int col = n0 + wn + ni*16 + qi;
        if (col < FFI){
          float va = aa[mi][ni][r] + b1[col];
          float vg = ag[mi][ni][r] + b1[FFI+col];
          hg[(size_t)row*FFIP + col] = f2bf(va * gelu_t(vg));
        } else if (col < FFIP){
          hg[(size_t)row*FFIP + col] = 0;
        }
      }
    }
  }
}

// ---------------- rotary/xpos tables (f64 precompute) ----------------
__global__ void rope_k(float* __restrict__ tab){
  int n = blockIdx.x, dd = threadIdx.x;
  int i = dd & 31;
  double invf = pow(10000.0, -(double)i/32.0);
  double fr = (double)n * invf;
  double c = cos(fr), s = sin(fr);
  double sv = (2.0*i + 25.6)/89.6;
  double pw = ((double)n - 4096.0)/128.0;
  double xs = pow(sv, pw);
  size_t o = (size_t)n*64 + dd;
  tab[o]            = (float)(c*xs);
  tab[524288+o]     = (float)(s*xs);
  tab[2*524288+o]   = (float)(c/xs);
  tab[3*524288+o]   = (float)(s/xs);
}

// ---------------- weight transpose+cast: dst[N][Kp] bf16 from src[K][N] f32, zero-pad K..Kp ----------------
__global__ __launch_bounds__(256) void wtrans_k(
    const float* __restrict__ src, short* __restrict__ dst,
    int K, int N, int Kp, long srcStride, long dstStride)
{
  __shared__ float t[64][65];
  const float* s = src + (size_t)blockIdx.z * srcStride;
  short* d = dst + (size_t)blockIdx.z * dstStride;
  int n0 = blockIdx.x*64, k0 = blockIdx.y*64;
  int tid = threadIdx.x;
  #pragma unroll
  for (int p=0;p<4;p++){
    int task = p*256+tid;
    int r = task>>4, c = (task&15)*4;
    int k = k0 + r;
    #pragma unroll
    for (int e=0;e<4;e++){
      int n = n0+c+e;
      t[r][c+e] = (k<K && n<N) ? s[(size_t)k*N+n] : 0.f;
    }
  }
  __syncthreads();
  #pragma unroll
  for (int p=0;p<2;p++){
    int task = p*256+tid;
    int nr = task>>3, kg=(task&7)*8;
    int n = n0+nr;
    if (n < N && (k0+kg) < Kp){
      s16x8 v;
      #pragma unroll
      for (int j=0;j<8;j++) v[j] = f2bf(t[kg+j][nr]);
      *(s16x8*)(d + (size_t)n*Kp + k0 + kg) = v;
    }
  }
}

// ---------------- f32 -> bf16 cast ----------------
__global__ void cast_k(const float* __restrict__ in, short* __restrict__ out){
  int i = (blockIdx.x*256+threadIdx.x)*4;
  float4 v = *(const float4*)(in+i);
  s16x4 o = { f2bf(v.x), f2bf(v.y), f2bf(v.z), f2bf(v.w) };
  *(s16x4*)(out+i) = o;
}

// ---------------- q/k: l2norm + scale + xpos rotary ----------------
__global__ __launch_bounds__(256) void qkprep_k(
    const short* __restrict__ qkv, const float* __restrict__ tab,
    const float* __restrict__ qs, const float* __restrict__ ks,
    short* __restrict__ qrot, short* __restrict__ krot)
{
  int wv = threadIdx.x >> 6, lane = threadIdx.x & 63;
  int wid = blockIdx.x*4 + wv;
  int n = wid >> 3, h = wid & 7;
  float qv = bf2f(qkv[(size_t)n*1536 + h*64 + lane]);
  float kv = bf2f(qkv[(size_t)n*1536 + 512 + h*64 + lane]);
  float sq = qv*qv, sk = kv*kv;
  #pragma unroll
  for (int m=1;m<64;m<<=1){ sq += __shfl_xor(sq,m,64); sk += __shfl_xor(sk,m,64); }
  qv *= qs[lane] / fmaxf(sqrtf(sq), 1e-12f);
  kv *= ks[lane] / fmaxf(sqrtf(sk), 1e-12f);
  float qo = __shfl_xor(qv,32,64), ko = __shfl_xor(kv,32,64);
  float sgn = (lane<32)? -1.f : 1.f;
  size_t to = (size_t)n*64 + lane;
  float cq = tab[to], sxq = tab[524288+to], ck = tab[2*524288+to], sxk = tab[3*524288+to];
  qrot[((size_t)h*8192+n)*64+lane] = f2bf(qv*cq + sgn*qo*sxq);
  krot[((size_t)h*8192+n)*64+lane] = f2bf(kv*ck + sgn*ko*sxk);
}

// ---------------- V transpose: vt[h][d][n] ----------------
__global__ __launch_bounds__(256) void vtrans_k(const short* __restrict__ qkv, short* __restrict__ vt){
  __shared__ short t[64][72];
  int n0 = blockIdx.x*64, h = blockIdx.y;
  int tid = threadIdx.x;
  #pragma unroll
  for (int p=0;p<2;p++){
    int task = p*256+tid;
    int r = task>>3, cg = (task&7)*8;
    *(s16x8*)&t[r][cg] = *(const s16x8*)(qkv + (size_t)(n0+r)*1536 + 1024 + h*64 + cg);
  }
  __syncthreads();
  #pragma unroll
  for (int p=0;p<2;p++){
    int task = p*256+tid;
    int d = task>>3, nb = (task&7)*8;
    s16x8 v;
    #pragma unroll
    for (int j=0;j<8;j++) v[j] = t[nb+j][d];
    *(s16x8*)(vt + ((size_t)h*64+d)*8192 + n0 + nb) = v;
  }
}

// ---------------- local windowed attention (S^T = K*Q^T formulation, flash over 64-key chunks) ----------------
__global__ __launch_bounds__(256,1) void attn_k(
    const short* __restrict__ qrot, const short* __restrict__ krot,
    const short* __restrict__ vt, short* __restrict__ attn_o)
{
  __shared__ short Ks[128][72];
  __shared__ short Vs[64][136];
  const int w = blockIdx.x, h = blockIdx.y;
  const int tid = threadIdx.x, lane = tid & 63, wv = tid >> 6;
  const int g = lane >> 4, qi = lane & 15;
  const int wq0 = wv * 64;
  s16x8 qf[4][2];
  #pragma unroll
  for (int ni=0;ni<4;ni++){
    int qg = w*256 + wq0 + ni*16 + qi;
    const short* p = qrot + ((size_t)h*8192 + qg)*64 + g*8;
    qf[ni][0] = *(const s16x8*)p;
    qf[ni][1] = *(const s16x8*)(p + 32);
  }
  f32x4 oacc[4][4];
  float mrun[4], lrun[4];
  #pragma unroll
  for (int i=0;i<4;i++){
    mrun[i] = -1e30f; lrun[i] = 0.f;
    #pragma unroll
    for (int j=0;j<4;j++) oacc[i][j]=(f32x4){0.f,0.f,0.f,0.f};
  }
  const int kvbase = w*256 - 256;
  for (int s=0;s<4;s++){
    __syncthreads();
    #pragma unroll
    for (int p=0;p<4;p++){
      int task = p*256 + tid;
      {
        int r = task>>3, cg = (task&7)*8;
        int jg = kvbase + s*128 + r;
        s16x8 v = {0,0,0,0,0,0,0,0};
        if (jg>=0) v = *(const s16x8*)(krot + ((size_t)h*8192+jg)*64 + cg);
        *(s16x8*)&Ks[r][cg] = v;
      }
      {
        int dd = task>>4, cg = (task&15)*8;
        int jg = kvbase + s*128 + cg;
        s16x8 v = {0,0,0,0,0,0,0,0};
        if (jg>=0) v = *(const s16x8*)(vt + ((size_t)h*64+dd)*8192 + jg);
        *(s16x8*)&Vs[dd][cg] = v;
      }
    }
    __syncthreads();
    for (int cc=0;cc<2;cc++){
      const int jlo = (s*2+cc)*64;
      if (jlo + 63 < wq0) continue;
      if (jlo > wq0 + 319) continue;
      if (w==0 && jlo < 256) continue;
      f32x4 sacc[4][4];
      #pragma unroll
      for (int i=0;i<4;i++)
        #pragma unroll
        for (int j=0;j<4;j++) sacc[i][j]=(f32x4){0.f,0.f,0.f,0.f};
      #pragma unroll
      for (int ks=0;ks<2;ks++){
        s16x8 kf[4];
        #pragma unroll
        for (int mi=0;mi<4;mi++) kf[mi] = *(const s16x8*)&Ks[cc*64+mi*16+qi][ks*32+g*8];
        #pragma unroll
        for (int mi=0;mi<4;mi++)
          #pragma unroll
          for (int ni=0;ni<4;ni++)
            sacc[mi][ni] = MFMA(kf[mi], qf[ni][ks], sacc[mi][ni]);
      }
      const bool interior = (jlo >= wq0+63) && (jlo+63 <= wq0+256);
      float cmax[4];
      #pragma unroll
      for (int ni=0;ni<4;ni++) cmax[ni] = -1e30f;
      #pragma unroll
      for (int mi=0;mi<4;mi++)
        #pragma unroll
        for (int ni=0;ni<4;ni++)
          #pragma unroll
          for (int r=0;r<4;r++){
            float x = sacc[mi][ni][r] * 8.f;
            if (!interior){
              int j = jlo + mi*16 + g*4 + r;
              int ql = wq0 + ni*16 + qi;
              if (j < ql || j > ql+256) x = -1e30f;
            }
            sacc[mi][ni][r] = x;
            cmax[ni] = fmaxf(cmax[ni], x);
          }
      #pragma unroll
      for (int ni=0;ni<4;ni++){
        cmax[ni] = fmaxf(cmax[ni], __shfl_xor(cmax[ni],16,64));
        cmax[ni] = fmaxf(cmax[ni], __shfl_xor(cmax[ni],32,64));
      }
      float scl[4], psum[4];
      s16x8 pf[2][4];
      #pragma unroll
      for (int ni=0;ni<4;ni++){
        float mn = fmaxf(mrun[ni], cmax[ni]);
        scl[ni] = __expf(mrun[ni]-mn);
        mrun[ni] = mn;
        float ps = 0.f;
        #pragma unroll
        for (int t=0;t<2;t++)
          #pragma unroll
          for (int hh=0; hh<2; hh++){
            int mi = 2*t+hh;
            #pragma unroll
            for (int r=0;r<4;r++){
              float pv = __expf(sacc[mi][ni][r]-mn);
              ps += pv;
              pf[t][ni][hh*4+r] = f2bf(pv);
            }
          }
        psum[ni]=ps;
      }
      #pragma unroll
      for (int ni=0;ni<4;ni++){
        psum[ni] += __shfl_xor(psum[ni],16,64);
        psum[ni] += __shfl_xor(psum[ni],32,64);
        lrun[ni] = lrun[ni]*scl[ni] + psum[ni];
        #pragma unroll
        for (int mi=0;mi<4;mi++) oacc[mi][ni] *= scl[ni];
      }
      #pragma unroll
      for (int t=0;t<2;t++)
        #pragma unroll
        for (int mi=0;mi<4;mi++){
          const short* vp = &Vs[mi*16+qi][cc*64 + t*32 + g*4];
          s16x4 lo = *(const s16x4*)vp;
          s16x4 hi = *(const s16x4*)(vp+16);
          s16x8 vf = {lo[0],lo[1],lo[2],lo[3],hi[0],hi[1],hi[2],hi[3]};
          #pragma unroll
          for (int ni=0;ni<4;ni++)
            oacc[mi][ni] = MFMA(vf, pf[t][ni], oacc[mi][ni]);
        }
    }
  }
  #pragma unroll
  for (int ni=0;ni<4;ni++){
    float inv = 1.f / lrun[ni];
    int qg = w*256 + wq0 + ni*16 + qi;
    #pragma unroll
    for (int mi=0;mi<4;mi++){
      s16x4 st;
      #pragma unroll
      for (int r=0;r<4;r++) st[r] = f2bf(oacc[mi][ni][r]*inv);
      *(s16x4*)(attn_o + (size_t)qg*512 + h*64 + mi*16 + g*4) = st;
    }
  }
}

extern "C" void kernel_launch(void* const* d_in, const int* in_sizes, int n_in,
                              void* d_out, int out_size, void* d_ws, size_t ws_size,
                              hipStream_t stream)
{
  const float* x_in = (const float*)d_in[0];
  const float* Wqkv = (const float*)d_in[1];
  const float* Wo   = (const float*)d_in[2];
  const float* qsc  = (const float*)d_in[3];
  const float* ksc  = (const float*)d_in[4];
  const float* W1   = (const float*)d_in[5];
  const float* b1   = (const float*)d_in[6];
  const float* W2   = (const float*)d_in[7];
  const float* b2   = (const float*)d_in[8];
  float* xf = (float*)d_out;

  char* ws = (char*)d_ws;
  size_t off = 0;
  float* tab  = (float*)(ws + off); off += (size_t)4*8192*64*4;
  short* WqkvT= (short*)(ws + off); off += (size_t)6*1536*512*2;
  short* WoT  = (short*)(ws + off); off += (size_t)6*512*512*2;
  short* W1T  = (short*)(ws + off); off += (size_t)6*2730*512*2;
  short* W2T  = (short*)(ws + off); off += (size_t)6*512*1376*2;
  short* xbf  = (short*)(ws + off); off += (size_t)8192*512*2;
  short* qkv  = (short*)(ws + off); off += (size_t)8192*1536*2;
  short* qrot = (short*)(ws + off); off += (size_t)8*8192*64*2;
  short* krot = (short*)(ws + off); off += (size_t)8*8192*64*2;
  short* vt   = (short*)(ws + off); off += (size_t)8*8192*64*2;
  short* attno= (short*)(ws + off); off += (size_t)8192*512*2;
  short* hg   = (short*)(ws + off); off += (size_t)8192*1376*2;

  hipMemcpyAsync(xf, x_in, (size_t)8192*512*4, hipMemcpyDeviceToDevice, stream);
  rope_k<<<8192, 64, 0, stream>>>(tab);
  wtrans_k<<<dim3(24,8,6),256,0,stream>>>(Wqkv, WqkvT, 512,1536,512, (long)512*1536, (long)1536*512);
  wtrans_k<<<dim3(8,8,6),256,0,stream>>>(Wo, WoT, 512,512,512, (long)512*512,(long)512*512);
  wtrans_k<<<dim3(43,8,6),256,0,stream>>>(W1, W1T, 512,2730,512, (long)512*2730,(long)2730*512);
  wtrans_k<<<dim3(8,22,6),256,0,stream>>>(W2, W2T, 1365,512,1376, (long)1365*512,(long)512*1376);
  cast_k<<<4096,256,0,stream>>>(x_in, xbf);

  for (int l=0;l<6;l++){
    gemm_k<0,0,0,1><<<dim3(64,12),256,0,stream>>>(xbf, WqkvT + (size_t)l*1536*512,
        nullptr, nullptr, nullptr, qkv, 8192,1536,512);
    qkprep_k<<<16384,256,0,stream>>>(qkv, tab, qsc + l*64, ksc + l*64, qrot, krot);
    vtrans_k<<<dim3(128,8),256,0,stream>>>(qkv, vt);
    attn_k<<<dim3(32,8),256,0,stream>>>(qrot, krot, vt, attno);
    gemm_k<0,1,1,1><<<dim3(64,4),256,0,stream>>>(attno, WoT + (size_t)l*512*512,
        nullptr, xf, xf, xbf, 8192,512,512);
    geglu_k<<<dim3(64,11),256,0,stream>>>(xbf, W1T + (size_t)l*2730*512, b1 + (size_t)l*2730, hg);
    gemm_k<1,1,1,1><<<dim3(64,4),256,0,stream>>>(hg, W2T + (size_t)l*512*1376,
        b2 + (size_t)l*512, xf, xf, xbf, 8192,512,1376);
  }
}

// Round 4
// 1200.455 us; speedup vs baseline: 1.3545x; 1.1999x over previous
//
#include <hip/hip_runtime.h>
#include <hip/hip_bf16.h>
#include <math.h>

typedef short s16x8 __attribute__((ext_vector_type(8)));
typedef short s16x4 __attribute__((ext_vector_type(4)));
typedef float f32x4 __attribute__((ext_vector_type(4)));

#define MFMA(A,B,C) __builtin_amdgcn_mfma_f32_16x16x32_bf16((A),(B),(C),0,0,0)

typedef __attribute__((address_space(3))) unsigned int lds_u32;
typedef __attribute__((address_space(1))) const unsigned int glb_u32;
__device__ __forceinline__ void gload16(const short* g, const short* l){
  __builtin_amdgcn_global_load_lds((glb_u32*)g, (lds_u32*)l, 16, 0, 0);
}

__device__ __forceinline__ float bf2f(short u){
  unsigned int x = ((unsigned int)(unsigned short)u) << 16;
  return __builtin_bit_cast(float, x);
}
__device__ __forceinline__ short f2bf(float f){
  unsigned int x = __builtin_bit_cast(unsigned int, f);
  x += 0x7fffu + ((x >> 16) & 1u);
  return (short)(x >> 16);
}
// tanh-form gelu, overflow-safe
__device__ __forceinline__ float gelu_t(float x){
  float u = x + 0.044715f*x*x*x;
  float e = __expf(1.5957691216057308f*u);
  float th = 1.f - 2.f/(e + 1.f);
  return 0.5f*x*(1.f + th);
}

// bijective XCD-chunk swizzle (m204 formula): same weight-panel blocks -> same XCD L2
__device__ __forceinline__ void xcd_swz(int gx, int gy, int &bx, int &by){
  int id = bx + by*gx;
  int nwg = gx*gy;
  int q = nwg >> 3, r = nwg & 7;
  int xcd = id & 7, idx = id >> 3;
  int nid = (xcd < r ? xcd*(q+1) : r*(q+1) + (xcd-r)*q) + idx;
  bx = nid % gx; by = nid / gx;
}

#define FFI 1365
#define FFIP 1376

// ---------------- GEMM: C = A[M][K] * Bt[N][K]^T (+bias)(+res); 512 thr, 8 waves, 2-phase dbuf ----------------
template<int HAS_BIAS, int HAS_RES, int OUT_F32, int OUT_BF16>
__global__ __launch_bounds__(512) void gemm_k(
    const short* __restrict__ A, const short* __restrict__ Bt,
    const float* __restrict__ bias, const float* __restrict__ res,
    float* __restrict__ outF, short* __restrict__ outB,
    int M, int N, int K)
{
  __shared__ short As[2][128*32];
  __shared__ short Bs[2][128*32];
  const int tid = threadIdx.x;
  const int lane = tid & 63, wv = tid >> 6;
  const int g = lane >> 4, qi = lane & 15;
  int bx = blockIdx.x, by = blockIdx.y;
  xcd_swz(gridDim.x, gridDim.y, bx, by);
  const int m0 = bx * 128, n0 = by * 128;
  const int wm = (wv >> 2) * 64, wn = (wv & 3) * 32;

  const int sr = tid >> 2, sc = (tid & 3) * 8;
  const short* Ag = A  + (size_t)(m0 + sr)*K + sc;
  const short* Bg = Bt + (size_t)(n0 + sr)*K + sc;

  f32x4 acc[4][2];
  #pragma unroll
  for (int i=0;i<4;i++)
    #pragma unroll
    for (int j=0;j<2;j++) acc[i][j] = (f32x4){0.f,0.f,0.f,0.f};

  auto stage = [&](int buf, int k0){
    gload16(Ag + k0, &As[buf][wv*512]);
    gload16(Bg + k0, &Bs[buf][wv*512]);
  };

  const int nt = K >> 5;
  stage(0, 0);
  __syncthreads();
  for (int t = 0; t < nt; ++t) {
    const int cur = t & 1;
    if (t + 1 < nt) stage(cur ^ 1, (t+1) << 5);
    s16x8 af[4], bf[2];
    #pragma unroll
    for (int mi=0;mi<4;mi++) af[mi] = *(const s16x8*)&As[cur][(wm+mi*16+qi)*32 + g*8];
    #pragma unroll
    for (int ni=0;ni<2;ni++) bf[ni] = *(const s16x8*)&Bs[cur][(wn+ni*16+qi)*32 + g*8];
    #pragma unroll
    for (int mi=0;mi<4;mi++)
      #pragma unroll
      for (int ni=0;ni<2;ni++)
        acc[mi][ni] = MFMA(af[mi], bf[ni], acc[mi][ni]);
    __syncthreads();
  }
  #pragma unroll
  for (int mi=0;mi<4;mi++){
    #pragma unroll
    for (int r=0;r<4;r++){
      int row = m0 + wm + mi*16 + g*4 + r;
      #pragma unroll
      for (int ni=0;ni<2;ni++){
        int col = n0 + wn + ni*16 + qi;
        float v = acc[mi][ni][r];
        if (HAS_BIAS) v += bias[col];
        if (HAS_RES)  v += res[(size_t)row*N + col];
        if (OUT_F32)  outF[(size_t)row*N + col] = v;
        if (OUT_BF16) outB[(size_t)row*N + col] = f2bf(v);
      }
    }
  }
}

// ---------------- FF1 + GEGLU fused ----------------
__global__ __launch_bounds__(512) void geglu_k(
    const short* __restrict__ A, const short* __restrict__ Bt,
    const float* __restrict__ b1, short* __restrict__ hg)
{
  __shared__ short As[2][128*32];
  __shared__ short Ba[2][128*32];
  __shared__ short Bg[2][128*32];
  const int tid = threadIdx.x;
  const int lane = tid & 63, wv = tid >> 6;
  const int g = lane >> 4, qi = lane & 15;
  int bx = blockIdx.x, by = blockIdx.y;
  xcd_swz(gridDim.x, gridDim.y, bx, by);
  const int m0 = bx * 128, n0 = by * 128;
  const int wm = (wv >> 2) * 64, wn = (wv & 3) * 32;

  const int sr = tid >> 2, sc = (tid & 3) * 8;
  const short* Ag = A + (size_t)(m0 + sr)*512 + sc;
  const short* Pa = Bt + (size_t)min(n0 + sr, FFI-1)*512 + sc;
  const short* Pg = Bt + (size_t)min(FFI + n0 + sr, 2729)*512 + sc;

  f32x4 aa[4][2], ag[4][2];
  #pragma unroll
  for (int i=0;i<4;i++)
    #pragma unroll
    for (int j=0;j<2;j++){ aa[i][j]=(f32x4){0.f,0.f,0.f,0.f}; ag[i][j]=(f32x4){0.f,0.f,0.f,0.f}; }

  auto stage = [&](int buf, int k0){
    gload16(Ag + k0, &As[buf][wv*512]);
    gload16(Pa + k0, &Ba[buf][wv*512]);
    gload16(Pg + k0, &Bg[buf][wv*512]);
  };

  stage(0, 0);
  __syncthreads();
  for (int t = 0; t < 16; ++t) {
    const int cur = t & 1;
    if (t + 1 < 16) stage(cur ^ 1, (t+1) << 5);
    s16x8 af[4], bfa[2], bfg[2];
    #pragma unroll
    for (int mi=0;mi<4;mi++) af[mi] = *(const s16x8*)&As[cur][(wm+mi*16+qi)*32 + g*8];
    #pragma unroll
    for (int ni=0;ni<2;ni++){ bfa[ni] = *(const s16x8*)&Ba[cur][(wn+ni*16+qi)*32 + g*8];
                              bfg[ni] = *(const s16x8*)&Bg[cur][(wn+ni*16+qi)*32 + g*8]; }
    #pragma unroll
    for (int mi=0;mi<4;mi++)
      #pragma unroll
      for (int ni=0;ni<2;ni++){
        aa[mi][ni] = MFMA(af[mi], bfa[ni], aa[mi][ni]);
        ag[mi][ni] = MFMA(af[mi], bfg[ni], ag[mi][ni]);
      }
    __syncthreads();
  }
  #pragma unroll
  for (int mi=0;mi<4;mi++){
    #pragma unroll
    for (int r=0;r<4;r++){
      int row = m0 + wm + mi*16 + g*4 + r;
      #pragma unroll
      for (int ni=0;ni<2;ni++){
        int col = n0 + wn + ni*16 + qi;
        if (col < FFI){
          float va = aa[mi][ni][r] + b1[col];
          float vg = ag[mi][ni][r] + b1[FFI+col];
          hg[(size_t)row*FFIP + col] = f2bf(va * gelu_t(vg));
        } else if (col < FFIP){
          hg[(size_t)row*FFIP + col] = 0;
        }
      }
    }
  }
}

// ---------------- rotary/xpos tables (f64 precompute) ----------------
__global__ void rope_k(float* __restrict__ tab){
  int n = blockIdx.x, dd = threadIdx.x;
  int i = dd & 31;
  double invf = pow(10000.0, -(double)i/32.0);
  double fr = (double)n * invf;
  double c = cos(fr), s = sin(fr);
  double sv = (2.0*i + 25.6)/89.6;
  double pw = ((double)n - 4096.0)/128.0;
  double xs = pow(sv, pw);
  size_t o = (size_t)n*64 + dd;
  tab[o]            = (float)(c*xs);
  tab[524288+o]     = (float)(s*xs);
  tab[2*524288+o]   = (float)(c/xs);
  tab[3*524288+o]   = (float)(s/xs);
}

// ---------------- weight transpose+cast ----------------
__global__ __launch_bounds__(256) void wtrans_k(
    const float* __restrict__ src, short* __restrict__ dst,
    int K, int N, int Kp, long srcStride, long dstStride)
{
  __shared__ float t[64][65];
  const float* s = src + (size_t)blockIdx.z * srcStride;
  short* d = dst + (size_t)blockIdx.z * dstStride;
  int n0 = blockIdx.x*64, k0 = blockIdx.y*64;
  int tid = threadIdx.x;
  #pragma unroll
  for (int p=0;p<4;p++){
    int task = p*256+tid;
    int r = task>>4, c = (task&15)*4;
    int k = k0 + r;
    #pragma unroll
    for (int e=0;e<4;e++){
      int n = n0+c+e;
      t[r][c+e] = (k<K && n<N) ? s[(size_t)k*N+n] : 0.f;
    }
  }
  __syncthreads();
  #pragma unroll
  for (int p=0;p<2;p++){
    int task = p*256+tid;
    int nr = task>>3, kg=(task&7)*8;
    int n = n0+nr;
    if (n < N && (k0+kg) < Kp){
      s16x8 v;
      #pragma unroll
      for (int j=0;j<8;j++) v[j] = f2bf(t[kg+j][nr]);
      *(s16x8*)(d + (size_t)n*Kp + k0 + kg) = v;
    }
  }
}

// ---------------- f32 -> bf16 cast ----------------
__global__ void cast_k(const float* __restrict__ in, short* __restrict__ out){
  int i = (blockIdx.x*256+threadIdx.x)*4;
  float4 v = *(const float4*)(in+i);
  s16x4 o = { f2bf(v.x), f2bf(v.y), f2bf(v.z), f2bf(v.w) };
  *(s16x4*)(out+i) = o;
}

// ---------------- q/k: l2norm + scale + xpos rotary ----------------
__global__ __launch_bounds__(256) void qkprep_k(
    const short* __restrict__ qkv, const float* __restrict__ tab,
    const float* __restrict__ qs, const float* __restrict__ ks,
    short* __restrict__ qrot, short* __restrict__ krot)
{
  int wv = threadIdx.x >> 6, lane = threadIdx.x & 63;
  int wid = blockIdx.x*4 + wv;
  int n = wid >> 3, h = wid & 7;
  float qv = bf2f(qkv[(size_t)n*1536 + h*64 + lane]);
  float kv = bf2f(qkv[(size_t)n*1536 + 512 + h*64 + lane]);
  float sq = qv*qv, sk = kv*kv;
  #pragma unroll
  for (int m=1;m<64;m<<=1){ sq += __shfl_xor(sq,m,64); sk += __shfl_xor(sk,m,64); }
  qv *= qs[lane] / fmaxf(sqrtf(sq), 1e-12f);
  kv *= ks[lane] / fmaxf(sqrtf(sk), 1e-12f);
  float qo = __shfl_xor(qv,32,64), ko = __shfl_xor(kv,32,64);
  float sgn = (lane<32)? -1.f : 1.f;
  size_t to = (size_t)n*64 + lane;
  float cq = tab[to], sxq = tab[524288+to], ck = tab[2*524288+to], sxk = tab[3*524288+to];
  qrot[((size_t)h*8192+n)*64+lane] = f2bf(qv*cq + sgn*qo*sxq);
  krot[((size_t)h*8192+n)*64+lane] = f2bf(kv*ck + sgn*ko*sxk);
}

// ---------------- V transpose: vt[h][d][n] ----------------
__global__ __launch_bounds__(256) void vtrans_k(const short* __restrict__ qkv, short* __restrict__ vt){
  __shared__ short t[64][72];
  int n0 = blockIdx.x*64, h = blockIdx.y;
  int tid = threadIdx.x;
  #pragma unroll
  for (int p=0;p<2;p++){
    int task = p*256+tid;
    int r = task>>3, cg = (task&7)*8;
    *(s16x8*)&t[r][cg] = *(const s16x8*)(qkv + (size_t)(n0+r)*1536 + 1024 + h*64 + cg);
  }
  __syncthreads();
  #pragma unroll
  for (int p=0;p<2;p++){
    int task = p*256+tid;
    int d = task>>3, nb = (task&7)*8;
    s16x8 v;
    #pragma unroll
    for (int j=0;j<8;j++) v[j] = t[nb+j][d];
    *(s16x8*)(vt + ((size_t)h*64+d)*8192 + n0 + nb) = v;
  }
}

// ---------------- local windowed attention: 512 thr, 8 waves x 32 q-rows ----------------
__global__ __launch_bounds__(512,1) void attn_k(
    const short* __restrict__ qrot, const short* __restrict__ krot,
    const short* __restrict__ vt, short* __restrict__ attn_o)
{
  __shared__ short Ks[128][72];
  __shared__ short Vs[64][136];
  const int w = blockIdx.x, h = blockIdx.y;
  const int tid = threadIdx.x, lane = tid & 63, wv = tid >> 6;
  const int g = lane >> 4, qi = lane & 15;
  const int wq0 = wv * 32;
  s16x8 qf[2][2];
  #pragma unroll
  for (int ni=0;ni<2;ni++){
    int qg = w*256 + wq0 + ni*16 + qi;
    const short* p = qrot + ((size_t)h*8192 + qg)*64 + g*8;
    qf[ni][0] = *(const s16x8*)p;
    qf[ni][1] = *(const s16x8*)(p + 32);
  }
  f32x4 oacc[4][2];
  float mrun[2], lrun[2];
  #pragma unroll
  for (int i=0;i<2;i++){
    mrun[i] = -1e30f; lrun[i] = 0.f;
    #pragma unroll
    for (int j=0;j<4;j++) oacc[j][i]=(f32x4){0.f,0.f,0.f,0.f};
  }
  const int kvbase = w*256 - 256;
  for (int s=0;s<4;s++){
    __syncthreads();
    #pragma unroll
    for (int p=0;p<2;p++){
      int task = p*512 + tid;
      {
        int r = task>>3, cg = (task&7)*8;
        int jg = kvbase + s*128 + r;
        s16x8 v = {0,0,0,0,0,0,0,0};
        if (jg>=0) v = *(const s16x8*)(krot + ((size_t)h*8192+jg)*64 + cg);
        *(s16x8*)&Ks[r][cg] = v;
      }
      {
        int dd = task>>4, cg = (task&15)*8;
        int jg = kvbase + s*128 + cg;
        s16x8 v = {0,0,0,0,0,0,0,0};
        if (jg>=0) v = *(const s16x8*)(vt + ((size_t)h*64+dd)*8192 + jg);
        *(s16x8*)&Vs[dd][cg] = v;
      }
    }
    __syncthreads();
    for (int cc=0;cc<2;cc++){
      const int jlo = (s*2+cc)*64;
      if (jlo + 63 < wq0) continue;
      if (jlo > wq0 + 287) continue;
      if (w==0 && jlo < 256) continue;
      f32x4 sacc[4][2];
      #pragma unroll
      for (int i=0;i<4;i++)
        #pragma unroll
        for (int j=0;j<2;j++) sacc[i][j]=(f32x4){0.f,0.f,0.f,0.f};
      #pragma unroll
      for (int ks=0;ks<2;ks++){
        s16x8 kf[4];
        #pragma unroll
        for (int mi=0;mi<4;mi++) kf[mi] = *(const s16x8*)&Ks[cc*64+mi*16+qi][ks*32+g*8];
        #pragma unroll
        for (int mi=0;mi<4;mi++)
          #pragma unroll
          for (int ni=0;ni<2;ni++)
            sacc[mi][ni] = MFMA(kf[mi], qf[ni][ks], sacc[mi][ni]);
      }
      const bool interior = (jlo >= wq0+31) && (jlo+63 <= wq0+256);
      float cmax[2];
      #pragma unroll
      for (int ni=0;ni<2;ni++) cmax[ni] = -1e30f;
      #pragma unroll
      for (int mi=0;mi<4;mi++)
        #pragma unroll
        for (int ni=0;ni<2;ni++)
          #pragma unroll
          for (int r=0;r<4;r++){
            float x = sacc[mi][ni][r] * 8.f;
            if (!interior){
              int j = jlo + mi*16 + g*4 + r;
              int ql = wq0 + ni*16 + qi;
              if (j < ql || j > ql+256) x = -1e30f;
            }
            sacc[mi][ni][r] = x;
            cmax[ni] = fmaxf(cmax[ni], x);
          }
      #pragma unroll
      for (int ni=0;ni<2;ni++){
        cmax[ni] = fmaxf(cmax[ni], __shfl_xor(cmax[ni],16,64));
        cmax[ni] = fmaxf(cmax[ni], __shfl_xor(cmax[ni],32,64));
      }
      float scl[2], psum[2];
      s16x8 pf[2][2];
      #pragma unroll
      for (int ni=0;ni<2;ni++){
        float mn = fmaxf(mrun[ni], cmax[ni]);
        scl[ni] = __expf(mrun[ni]-mn);
        mrun[ni] = mn;
        float ps = 0.f;
        #pragma unroll
        for (int t=0;t<2;t++)
          #pragma unroll
          for (int hh=0; hh<2; hh++){
            int mi = 2*t+hh;
            #pragma unroll
            for (int r=0;r<4;r++){
              float pv = __expf(sacc[mi][ni][r]-mn);
              ps += pv;
              pf[t][ni][hh*4+r] = f2bf(pv);
            }
          }
        psum[ni]=ps;
      }
      #pragma unroll
      for (int ni=0;ni<2;ni++){
        psum[ni] += __shfl_xor(psum[ni],16,64);
        psum[ni] += __shfl_xor(psum[ni],32,64);
        lrun[ni] = lrun[ni]*scl[ni] + psum[ni];
        #pragma unroll
        for (int mi=0;mi<4;mi++) oacc[mi][ni] *= scl[ni];
      }
      #pragma unroll
      for (int t=0;t<2;t++)
        #pragma unroll
        for (int mi=0;mi<4;mi++){
          const short* vp = &Vs[mi*16+qi][cc*64 + t*32 + g*4];
          s16x4 lo = *(const s16x4*)vp;
          s16x4 hi = *(const s16x4*)(vp+16);
          s16x8 vf = {lo[0],lo[1],lo[2],lo[3],hi[0],hi[1],hi[2],hi[3]};
          #pragma unroll
          for (int ni=0;ni<2;ni++)
            oacc[mi][ni] = MFMA(vf, pf[t][ni], oacc[mi][ni]);
        }
    }
  }
  #pragma unroll
  for (int ni=0;ni<2;ni++){
    float inv = 1.f / lrun[ni];
    int qg = w*256 + wq0 + ni*16 + qi;
    #pragma unroll
    for (int mi=0;mi<4;mi++){
      s16x4 st;
      #pragma unroll
      for (int r=0;r<4;r++) st[r] = f2bf(oacc[mi][ni][r]*inv);
      *(s16x4*)(attn_o + (size_t)qg*512 + h*64 + mi*16 + g*4) = st;
    }
  }
}

extern "C" void kernel_launch(void* const* d_in, const int* in_sizes, int n_in,
                              void* d_out, int out_size, void* d_ws, size_t ws_size,
                              hipStream_t stream)
{
  const float* x_in = (const float*)d_in[0];
  const float* Wqkv = (const float*)d_in[1];
  const float* Wo   = (const float*)d_in[2];
  const float* qsc  = (const float*)d_in[3];
  const float* ksc  = (const float*)d_in[4];
  const float* W1   = (const float*)d_in[5];
  const float* b1   = (const float*)d_in[6];
  const float* W2   = (const float*)d_in[7];
  const float* b2   = (const float*)d_in[8];
  float* xf = (float*)d_out;

  char* ws = (char*)d_ws;
  size_t off = 0;
  float* tab  = (float*)(ws + off); off += (size_t)4*8192*64*4;
  short* WqkvT= (short*)(ws + off); off += (size_t)6*1536*512*2;
  short* WoT  = (short*)(ws + off); off += (size_t)6*512*512*2;
  short* W1T  = (short*)(ws + off); off += (size_t)6*2730*512*2;
  short* W2T  = (short*)(ws + off); off += (size_t)6*512*1376*2;
  short* xbf  = (short*)(ws + off); off += (size_t)8192*512*2;
  short* qkv  = (short*)(ws + off); off += (size_t)8192*1536*2;
  short* qrot = (short*)(ws + off); off += (size_t)8*8192*64*2;
  short* krot = (short*)(ws + off); off += (size_t)8*8192*64*2;
  short* vt   = (short*)(ws + off); off += (size_t)8*8192*64*2;
  short* attno= (short*)(ws + off); off += (size_t)8192*512*2;
  short* hg   = (short*)(ws + off); off += (size_t)8192*1376*2;

  hipMemcpyAsync(xf, x_in, (size_t)8192*512*4, hipMemcpyDeviceToDevice, stream);
  rope_k<<<8192, 64, 0, stream>>>(tab);
  wtrans_k<<<dim3(24,8,6),256,0,stream>>>(Wqkv, WqkvT, 512,1536,512, (long)512*1536, (long)1536*512);
  wtrans_k<<<dim3(8,8,6),256,0,stream>>>(Wo, WoT, 512,512,512, (long)512*512,(long)512*512);
  wtrans_k<<<dim3(43,8,6),256,0,stream>>>(W1, W1T, 512,2730,512, (long)512*2730,(long)2730*512);
  wtrans_k<<<dim3(8,22,6),256,0,stream>>>(W2, W2T, 1365,512,1376, (long)1365*512,(long)512*1376);
  cast_k<<<4096,256,0,stream>>>(x_in, xbf);

  for (int l=0;l<6;l++){
    gemm_k<0,0,0,1><<<dim3(64,12),512,0,stream>>>(xbf, WqkvT + (size_t)l*1536*512,
        nullptr, nullptr, nullptr, qkv, 8192,1536,512);
    qkprep_k<<<16384,256,0,stream>>>(qkv, tab, qsc + l*64, ksc + l*64, qrot, krot);
    vtrans_k<<<dim3(128,8),256,0,stream>>>(qkv, vt);
    attn_k<<<dim3(32,8),512,0,stream>>>(qrot, krot, vt, attno);
    gemm_k<0,1,1,1><<<dim3(64,4),512,0,stream>>>(attno, WoT + (size_t)l*512*512,
        nullptr, xf, xf, xbf, 8192,512,512);
    geglu_k<<<dim3(64,11),512,0,stream>>>(xbf, W1T + (size_t)l*2730*512, b1 + (size_t)l*2730, hg);
    gemm_k<1,1,1,1><<<dim3(64,4),512,0,stream>>>(hg, W2T + (size_t)l*512*1376,
        b2 + (size_t)l*512, xf, xf, xbf, 8192,512,1376);
  }
}